// Round 5
// baseline (300.811 us; speedup 1.0000x reference)
//
#include <hip/hip_runtime.h>

// DCE-MRI eTofts forward model — 2-way T-split per row (re-scan trick).
// param: [B,3] f32, T10: [B,1] f32, cp: [B,T] f32  ->  out: [B,T] f32
//
// TLP was capped at 16 waves/CU by the 1-row-per-lane structure (4096 waves).
// Split each row's T=112 across TWO lanes: lane h=0 owns t in [0,56), lane
// h=1 owns t in [56,112). Wave = 32 rows -> 8192 waves = 32/CU (wave-slot
// saturation).
//
// Re-scan trick (bitwise-exact): pass 1 runs the bare IIR scan c=c*d+cp*DT
// per lane over its own half (per-lane scattered reads of its own row-half;
// the wave's 64 lanes collectively cover every byte of the 32-row slab, so
// no over-fetch, and it primes L2). A single __shfl hands lo's end value
// c[55] to the hi lane. Phase 2 re-runs the plain recurrence from the
// correct init with full downstream (exp/div) through the R4-style LDS
// transpose pipeline. Since a re-scan with correct init IS the original
// recurrence continued, outputs are bitwise identical to the R4 kernel.
//
// Phase-2 LDS: one slot per wave, 8-t half-tiles, word = (h*8+tt)*33 + row.
// Compute access: bank = (8h + s + row) mod 32 -> each bank exactly 2
// lanes = free. Stage/gather are ~4-way (16 ds ops/tile, off critical path).
// No barriers anywhere: wave-private LDS, DS pipe is in-order per wave
// (precedent: R3/R4 passed barrier-free).
//
// __launch_bounds__(256, 8) pins VGPR <= 64 so 8 waves/SIMD stay resident.
// Loads are cached (L2 reuse is the point); only stores are nontemporal.

typedef float f32x4 __attribute__((ext_vector_type(4)));

static constexpr int   Bn    = 262144;
static constexpr int   Tn    = 112;
static constexpr int   Hh    = 56;         // half length
static constexpr int   TTt   = 8;          // timesteps per half-tile
static constexpr int   NTt   = 7;          // tiles (7*8 = 56 per half)
static constexpr int   LP    = 33;         // LDS word stride between t-rows
static constexpr float TRc   = 0.005f;
static constexpr float DELTT = 0.075f;                 // 4.5/60
static constexpr float R1R   = 4.5f;
static constexpr float SIN_A = 0.25881904510252074f;   // sin(15 deg)
static constexpr float COS_A = 0.9659258262890683f;    // cos(15 deg)

__global__ __launch_bounds__(256, 8) void etofts_kernel(
    const float* __restrict__ param,
    const float* __restrict__ T10,
    const float* __restrict__ cp,
    float* __restrict__ out)
{
    __shared__ float lds[4][16 * LP];      // 4 waves x 2112 B = 8448 B per WG

    const int tid = threadIdx.x;
    const int w   = tid >> 6;              // wave id within block
    const int l   = tid & 63;              // lane
    float* __restrict__ sl = lds[w];       // wave-private LDS region

    const int r32 = l & 31;                // row within this wave's slab
    const int h   = l >> 5;                // half: 0 -> t<56, 1 -> t>=56
    const int b0  = blockIdx.x * 128 + w * 32;  // wave's first row
    const int row = b0 + r32;              // this lane's row

    // Parameter scaling + clamping (2 lanes per row load the same params)
    const float ktrans = fminf(fmaxf(param[3 * row + 0] * 0.2f, 1e-5f), 0.2f);
    const float vp     = fminf(fmaxf(param[3 * row + 1] * 0.1f, 0.0005f), 0.1f);
    const float ve     = fminf(fmaxf(param[3 * row + 2] * 0.6f, 0.04f), 0.6f);
    const float decay  = __expf(-(ktrans / ve) * DELTT);
    const float r10    = 1.0f / T10[row];

    // ---- pass 1: bare scan of own half (scattered reads; primes L2) ----
    const float* half = cp + (size_t)row * Tn + h * Hh;
    float e = 0.0f;
    #pragma unroll
    for (int m = 0; m < 14; ++m) {
        const f32x4 a = *(const f32x4*)(half + 4 * m);
        e = fmaf(e, decay, a.x * DELTT);
        e = fmaf(e, decay, a.y * DELTT);
        e = fmaf(e, decay, a.z * DELTT);
        e = fmaf(e, decay, a.w * DELTT);
    }

    // hand lo's c[55] to the hi lane of the same row (intra-wave, lockstep)
    const float c55 = __shfl(e, r32);      // lane r32 = this row's lo lane
    float c = h ? c55 : 0.0f;              // phase-2 init

    // Phase-2 per-lane load/stage/store mapping:
    // instr i in {0,1}: rows i*16 + (l>>2); p = l&3 selects (half, 16B chunk)
    const int rr  = l >> 2;                // 0..15
    const int p   = l & 3;
    const int hh  = p >> 1;                // which half this lane stages
    const int tt0 = (p & 1) * 4;           // t-offset within half-tile (0|4)

    // ---- prefetch tile 0 (coalesced 16 B chunks, cached) ----
    f32x4 rb[2];
    #pragma unroll
    for (int i = 0; i < 2; ++i)
        rb[i] = *(const f32x4*)(cp + (size_t)(b0 + i * 16 + rr) * Tn
                                + hh * Hh + tt0);

    #pragma unroll
    for (int k = 0; k < NTt; ++k) {
        // ---- stage tile k into transposed LDS ----
        #pragma unroll
        for (int i = 0; i < 2; ++i) {
            const int ri = i * 16 + rr;
            sl[(hh * 8 + tt0 + 0) * LP + ri] = rb[i].x;
            sl[(hh * 8 + tt0 + 1) * LP + ri] = rb[i].y;
            sl[(hh * 8 + tt0 + 2) * LP + ri] = rb[i].z;
            sl[(hh * 8 + tt0 + 3) * LP + ri] = rb[i].w;
        }

        // ---- issue tile k+1 loads (hide latency behind compute) ----
        if (k + 1 < NTt) {
            #pragma unroll
            for (int i = 0; i < 2; ++i)
                rb[i] = *(const f32x4*)(cp + (size_t)(b0 + i * 16 + rr) * Tn
                                        + hh * Hh + (k + 1) * TTt + tt0);
        }

        // ---- compute 8 steps in place (own word: no cross-lane race) ----
        #pragma unroll
        for (int s = 0; s < TTt; ++s) {
            const int wd  = (h * 8 + s) * LP + r32;
            const float cpt = sl[wd];
            c = fmaf(c, decay, cpt * DELTT);             // IIR recurrence
            const float ct = fmaf(c, ktrans, vp * cpt);  // vp*cp + ce
            const float E  = __expf(-TRc * fmaf(R1R, ct, r10));
            sl[wd] = __fdividef((1.0f - E) * (SIN_A * 20.0f),
                                fmaf(-E, COS_A, 1.0f));
        }

        // ---- gather + coalesced nontemporal store ----
        #pragma unroll
        for (int i = 0; i < 2; ++i) {
            const int ri = i * 16 + rr;
            f32x4 o;
            o.x = sl[(hh * 8 + tt0 + 0) * LP + ri];
            o.y = sl[(hh * 8 + tt0 + 1) * LP + ri];
            o.z = sl[(hh * 8 + tt0 + 2) * LP + ri];
            o.w = sl[(hh * 8 + tt0 + 3) * LP + ri];
            __builtin_nontemporal_store(
                o, (f32x4*)(out + (size_t)(b0 + i * 16 + rr) * Tn
                            + hh * Hh + k * TTt + tt0));
        }
        // next stage's ds_writes are WAR-ordered after these ds_reads (DS
        // pipe in-order within a wave) — no barrier needed
    }
}

extern "C" void kernel_launch(void* const* d_in, const int* in_sizes, int n_in,
                              void* d_out, int out_size, void* d_ws, size_t ws_size,
                              hipStream_t stream) {
    const float* param = (const float*)d_in[0];
    const float* T10   = (const float*)d_in[1];
    const float* cp    = (const float*)d_in[2];
    float*       out   = (float*)d_out;

    const int threads = 256;               // 4 autonomous waves x 32 rows
    const int blocks  = Bn / 128;          // 2048 WGs -> 8192 waves = 32/CU
    etofts_kernel<<<blocks, threads, 0, stream>>>(param, T10, cp, out);
}

// Round 6
// 236.116 us; speedup vs baseline: 1.2740x; 1.2740x over previous
//
#include <hip/hip_runtime.h>

// DCE-MRI eTofts forward model — R4 structure + depth-2 load pipeline.
// param: [B,3] f32, T10: [B,1] f32, cp: [B,T] f32  ->  out: [B,T] f32
//
// Structure (proven best, R4 = 72 us rocprof): block = 128 threads = 2
// autonomous waves; each wave owns 64 rows + a PRIVATE LDS region; NO
// barriers (intra-wave DS ordering is in-order; R3/R4 passed barrier-free).
// T tiled 7 x 16: one aligned 64 B line per row-tile. LDS transposed
// [t][row], stride LP=66 — both access phases exactly 2 lanes/bank = free
// (verified 0 conflicts in R3/R4).
//
// NEW (the R5 post-mortem lesson): time tracks continuity of per-wave memory
// demand, not occupancy (R5: occ 54%, 2x slower). R4's load queue drained
// during every tile's compute+store (~45% of each tile period with zero
// outstanding loads -> 3.1 TB/s ~= 55% of sustainable). Fix: double-buffered
// register prefetch r[2][4], tile k+2 issued while staging tile k, so the
// stage-wait is a counted vmcnt (tile k oldest, tile k+1 + stores still in
// flight) and demand never drains. Full unroll keeps all r[][] indices
// compile-time (rule #20: runtime-indexed ext_vector arrays spill).

typedef float f32x4 __attribute__((ext_vector_type(4)));

static constexpr int   Bn    = 262144;
static constexpr int   Tn    = 112;
static constexpr int   TT    = 16;         // timesteps per tile (64 B per row-tile)
static constexpr int   NT    = Tn / TT;    // 7 tiles
static constexpr int   LP    = 66;         // LDS word stride between t-rows
static constexpr float TRc   = 0.005f;
static constexpr float DELTT = 0.075f;                 // 4.5/60
static constexpr float R1R   = 4.5f;
static constexpr float SIN_A = 0.25881904510252074f;   // sin(15 deg)
static constexpr float COS_A = 0.9659258262890683f;    // cos(15 deg)

__global__ __launch_bounds__(128, 4) void etofts_kernel(
    const float* __restrict__ param,
    const float* __restrict__ T10,
    const float* __restrict__ cp,
    float* __restrict__ out)
{
    __shared__ float lds[2][TT * LP];      // 2 x 4224 B = 8448 B per WG

    const int tid = threadIdx.x;
    const int w   = tid >> 6;              // wave id within block
    const int l   = tid & 63;              // lane
    float* __restrict__ sl = lds[w];       // wave-private LDS region

    const int b0 = blockIdx.x * 128 + w * 64;  // this wave's first row
    const int b  = b0 + l;                     // this lane's own row

    // Per-lane mapping: row = i*16 + (l>>2), c4 = l&3; each 4-lane group
    // covers one contiguous aligned 64 B line.
    const int rsub = l >> 2;               // 0..15
    const int c4   = l & 3;                // 0..3
    const int tb   = c4 * 4;               // first timestep of this float4

    // ---- prologue: issue tiles 0 and 1 (depth-2 pipeline fill) ----
    f32x4 r[2][4];
    #pragma unroll
    for (int i = 0; i < 4; ++i) {
        const int row = i * 16 + rsub;
        r[0][i] = __builtin_nontemporal_load(
            (const f32x4*)(cp + (size_t)(b0 + row) * Tn + 0 * TT + c4 * 4));
    }
    #pragma unroll
    for (int i = 0; i < 4; ++i) {
        const int row = i * 16 + rsub;
        r[1][i] = __builtin_nontemporal_load(
            (const f32x4*)(cp + (size_t)(b0 + row) * Tn + 1 * TT + c4 * 4));
    }

    // Parameter scaling + clamping
    const float ktrans = fminf(fmaxf(param[3 * b + 0] * 0.2f, 1e-5f), 0.2f);
    const float vp     = fminf(fmaxf(param[3 * b + 1] * 0.1f, 0.0005f), 0.1f);
    const float ve     = fminf(fmaxf(param[3 * b + 2] * 0.6f, 0.04f), 0.6f);
    const float decay  = __expf(-(ktrans / ve) * DELTT);
    const float r10    = 1.0f / T10[b];

    float c = 0.0f;                        // IIR state across tiles

    #pragma unroll
    for (int tile = 0; tile < NT; ++tile) {
        const int cur = tile & 1;          // compile-time after full unroll

        // ---- stage tile `tile` into transposed LDS ----
        // (counted vmcnt: waits only the 4 OLDEST loads; tile+1's loads and
        //  prior stores remain in flight — demand queue never drains)
        #pragma unroll
        for (int i = 0; i < 4; ++i) {
            const int row = i * 16 + rsub;
            const f32x4 v = r[cur][i];
            sl[(tb + 0) * LP + row] = v.x;
            sl[(tb + 1) * LP + row] = v.y;
            sl[(tb + 2) * LP + row] = v.z;
            sl[(tb + 3) * LP + row] = v.w;
        }

        // ---- refill this buffer with tile+2 (keep 2 tiles in flight) ----
        if (tile + 2 < NT) {
            #pragma unroll
            for (int i = 0; i < 4; ++i) {
                const int row = i * 16 + rsub;
                r[cur][i] = __builtin_nontemporal_load(
                    (const f32x4*)(cp + (size_t)(b0 + row) * Tn
                                   + (tile + 2) * TT + c4 * 4));
            }
        }

        // ---- compute 16 steps in place (own column: no cross-lane race) ----
        #pragma unroll
        for (int t = 0; t < TT; ++t) {
            const float cpt = sl[t * LP + l];
            c = fmaf(c, decay, cpt * DELTT);             // IIR recurrence
            const float ct = fmaf(c, ktrans, vp * cpt);  // vp*cp + ce
            const float E  = __expf(-TRc * fmaf(R1R, ct, r10));
            sl[t * LP + l] = __fdividef((1.0f - E) * (SIN_A * 20.0f),
                                        fmaf(-E, COS_A, 1.0f));
        }

        // ---- coalesced full-line nontemporal store ----
        #pragma unroll
        for (int i = 0; i < 4; ++i) {
            const int row = i * 16 + rsub;
            f32x4 o;
            o.x = sl[(tb + 0) * LP + row];
            o.y = sl[(tb + 1) * LP + row];
            o.z = sl[(tb + 2) * LP + row];
            o.w = sl[(tb + 3) * LP + row];
            __builtin_nontemporal_store(
                o, (f32x4*)(out + (size_t)(b0 + row) * Tn + tile * TT + c4 * 4));
        }
        // (no barrier: next stage's ds_writes are WAR-ordered by the in-order
        //  DS pipe within the wave)
    }
}

extern "C" void kernel_launch(void* const* d_in, const int* in_sizes, int n_in,
                              void* d_out, int out_size, void* d_ws, size_t ws_size,
                              hipStream_t stream) {
    const float* param = (const float*)d_in[0];
    const float* T10   = (const float*)d_in[1];
    const float* cp    = (const float*)d_in[2];
    float*       out   = (float*)d_out;

    const int threads = 128;
    const int blocks  = Bn / 128;          // 2048 two-wave workgroups
    etofts_kernel<<<blocks, threads, 0, stream>>>(param, T10, cp, out);
}